// Round 8
// baseline (311.390 us; speedup 1.0000x reference)
//
#include <hip/hip_runtime.h>

#define Bz 64
#define Nn 577
#define Cc 768
#define Hh 12
#define Dd 64
#define SCALE 0.125f
#define YSEG 8

typedef __attribute__((ext_vector_type(8))) short short8;
typedef __attribute__((ext_vector_type(4))) float float4v;

__device__ __forceinline__ unsigned short bf16rne(float f) {
  unsigned u = __float_as_uint(f);
  u += 0x7FFFu + ((u >> 16) & 1u);
  return (unsigned short)(u >> 16);
}

__device__ __forceinline__ short8 cvt8(float4 a, float4 b) {
  short8 v;
  v[0] = (short)bf16rne(a.x); v[1] = (short)bf16rne(a.y);
  v[2] = (short)bf16rne(a.z); v[3] = (short)bf16rne(a.w);
  v[4] = (short)bf16rne(b.x); v[5] = (short)bf16rne(b.y);
  v[6] = (short)bf16rne(b.z); v[7] = (short)bf16rne(b.w);
  return v;
}

__device__ __forceinline__ short8 cvt8v(float4v a, float4v b) {
  short8 v;
  v[0] = (short)bf16rne(a[0]); v[1] = (short)bf16rne(a[1]);
  v[2] = (short)bf16rne(a[2]); v[3] = (short)bf16rne(a[3]);
  v[4] = (short)bf16rne(b[0]); v[5] = (short)bf16rne(b[1]);
  v[6] = (short)bf16rne(b[2]); v[7] = (short)bf16rne(b[3]);
  return v;
}

// ws layout (float units), main tier (needs ~24.4 MB):
//   rb     @ 0        : 786,432 bf16 (393,216 float slots) [B][24 s][4 q][16 m=h][8 j]
//   qf     @ 393216   : (unused in main tier)
//   logits @ 442368   : [B][H][N] fp32
//   attnT  @ 885504   : [B][N][H] fp32 (Tier C only)
//   ypart  @ 1328640  : [B][YSEG][H][C] fp32 (plain stores, summed in gemm<1>)
//   cls    @ 6047232  : [B][C] fp32
// Tier C (needs 7.87 MB): y @ 1328640 (atomic), cls @ 1918464.

// ============ k_gemm64: C(64 x 768) = A(64 x 768) @ W_rows^T + bias ===========
// MODE 1: cls = Y_h @ Wv^T     (A = ypart[b][seg][h=jt>>2]; SEGS summed; W rows 2C+j)
// MODE 2: out0 = cls @ projW^T (A row stride Cc;     W rows j;        out row0)
template <int MODE, int SEGS>
__global__ __launch_bounds__(256) void k_gemm64(const float* __restrict__ A,
                                                const float* __restrict__ W,
                                                const float* __restrict__ bias,
                                                float* __restrict__ out) {
  int tile = blockIdx.x;            // 0..191
  int jt = tile % 48, bt = tile / 48;
  int wave = threadIdx.x >> 6, lane = threadIdx.x & 63;
  int m = lane & 15, quad = lane >> 4;
  int brow = bt * 16 + m;
  int jrow = jt * 16 + m;
  size_t aoff;
  if (MODE == 0)      aoff = (size_t)brow * (Nn * Cc);
  else if (MODE == 1) aoff = (size_t)brow * (SEGS * Hh * Cc) + (size_t)(jt >> 2) * Cc;
  else                aoff = (size_t)brow * Cc;
  size_t woff = (MODE == 1) ? (size_t)(2 * Cc + jrow) * Cc : (size_t)jrow * Cc;
  const float4v* Ap = (const float4v*)(A + aoff) + wave * 48 + quad * 2;
  const float4v* Wp = (const float4v*)(W + woff) + wave * 48 + quad * 2;
  float4v acc = {0.f, 0.f, 0.f, 0.f};
#pragma unroll
  for (int s = 0; s < 6; ++s) {
    float4v a0, a1;
    if (MODE == 1 && SEGS > 1) {
      a0 = (float4v){0.f, 0.f, 0.f, 0.f};
      a1 = a0;
#pragma unroll
      for (int seg = 0; seg < SEGS; ++seg) {
        a0 += Ap[seg * 2304 + s * 8];      // 2304 = H*C/4 float4 per seg
        a1 += Ap[seg * 2304 + s * 8 + 1];
      }
    } else {
      a0 = Ap[s * 8]; a1 = Ap[s * 8 + 1];
    }
    float4v w0 = Wp[s * 8], w1 = Wp[s * 8 + 1];
    acc = __builtin_amdgcn_mfma_f32_16x16x32_bf16(cvt8v(a0, a1), cvt8v(w0, w1),
                                                  acc, 0, 0, 0);
  }
  __shared__ float red[4][64][4];
#pragma unroll
  for (int reg = 0; reg < 4; ++reg) red[wave][lane][reg] = acc[reg];
  __syncthreads();
  if (wave == 0) {
#pragma unroll
    for (int reg = 0; reg < 4; ++reg) {
      float v = red[0][lane][reg] + red[1][lane][reg] +
                red[2][lane][reg] + red[3][lane][reg];
      int j = jt * 16 + m;
      int bb = bt * 16 + quad * 4 + reg;
      float bv = (MODE == 1) ? bias[2 * Cc + j] : bias[j];
      if (MODE == 2) out[(size_t)bb * (Nn * Cc) + j] = v + bv;
      else           out[(size_t)bb * Cc + j] = v + bv;
    }
  }
}

// ====== k_rq: fused q-projection + r computation ==============================
// Block (h, bg of 4 b), grid 192 x 256 threads.
// Phase A: q[bb][d] = x0[bb] . Wq[h*64+d] + bq  (one q per thread, x0 in LDS)
// Phase B: rb[b][s][q][h][j] = bf16(SCALE * sum_d q * Wk[h,d,c])  (proven body)
__global__ __launch_bounds__(256) void k_rq(const float* __restrict__ x,
                                            const float* __restrict__ qkv_w,
                                            const float* __restrict__ qkv_b,
                                            unsigned short* __restrict__ rb) {
  int h = blockIdx.x % Hh, bg = blockIdx.x / Hh;   // bg 0..15
  int t = threadIdx.x;
  __shared__ float x0s[4 * Cc];                    // 12 KB: rows n=0 of 4 b
  __shared__ float qs2[Dd][4];
  {
    const float4v* xg = (const float4v*)x;
#pragma unroll
    for (int k = 0; k < 3; ++k) {
      int slot = t + k * 256;                      // 0..767 float4 slots
      int bb = slot / 192, c4 = slot % 192;
      ((float4v*)x0s)[slot] = xg[(size_t)(bg * 4 + bb) * 110784 + c4];
    }
  }
  __syncthreads();
  {
    int d = t & 63, bb = t >> 6;
    const float4v* wrow = (const float4v*)(qkv_w + (size_t)(h * Dd + d) * Cc);
    const float4v* xr = (const float4v*)x0s + bb * 192;
    float4v a = {0.f, 0.f, 0.f, 0.f};
#pragma unroll 4
    for (int c = 0; c < 192; ++c) a += wrow[c] * xr[c];
    qs2[d][bb] = a[0] + a[1] + a[2] + a[3] + qkv_b[h * Dd + d];
  }
  __syncthreads();
  float acc[4][3];
#pragma unroll
  for (int bb = 0; bb < 4; ++bb)
#pragma unroll
    for (int i = 0; i < 3; ++i) acc[bb][i] = 0.f;
  const float* wk = qkv_w + (size_t)(Cc + h * Dd) * Cc;
  for (int d = 0; d < Dd; ++d) {
    float w0 = wk[(size_t)d * Cc + t];
    float w1 = wk[(size_t)d * Cc + t + 256];
    float w2 = wk[(size_t)d * Cc + t + 512];
    float4 qa = *(const float4*)&qs2[d][0];
    float qv[4] = {qa.x, qa.y, qa.z, qa.w};
#pragma unroll
    for (int bb = 0; bb < 4; ++bb) {
      acc[bb][0] += qv[bb] * w0;
      acc[bb][1] += qv[bb] * w1;
      acc[bb][2] += qv[bb] * w2;
    }
  }
#pragma unroll
  for (int bb = 0; bb < 4; ++bb) {
    size_t base = (size_t)(bg * 4 + bb) * 12288 + h * 8;
#pragma unroll
    for (int i = 0; i < 3; ++i) {
      int c = t + i * 256;
      int s = c >> 5, qq = (c >> 3) & 3, j = c & 7;
      rb[base + s * 512 + qq * 128 + j] = bf16rne(acc[bb][i] * SCALE);
    }
  }
}

// ===== k_logits: MFMA straight from global (round-6 proven version) ===========
__global__ __launch_bounds__(256) void k_logits(const float* __restrict__ x,
                                                const unsigned short* __restrict__ rb,
                                                float* __restrict__ logits) {
  int b = blockIdx.x / 10, tile = blockIdx.x % 10;
  int wave = threadIdx.x >> 6, lane = threadIdx.x & 63;
  int m = lane & 15, quad = lane >> 4;
  int n = tile * 64 + wave * 16 + m;
  int nc = n > 576 ? 576 : n;
  const short8* ag = (const short8*)(rb + (size_t)b * 12288);
  const float4* xg = (const float4*)(x + (size_t)b * Nn * Cc) + (size_t)nc * 192 + quad * 2;
  float4v acc = {0.f, 0.f, 0.f, 0.f};
#pragma unroll 8
  for (int s = 0; s < 24; ++s) {
    short8 a = ag[s * 64 + quad * 16 + m];
    float4 f0 = xg[s * 8], f1 = xg[s * 8 + 1];
    acc = __builtin_amdgcn_mfma_f32_16x16x32_bf16(a, cvt8(f0, f1), acc, 0, 0, 0);
  }
  if (n < Nn) {
#pragma unroll
    for (int reg = 0; reg < 4; ++reg) {
      int hh = quad * 4 + reg;
      if (hh < Hh) logits[((size_t)b * Hh + hh) * Nn + n] = acc[reg];
    }
  }
}

// ---------------- softmax (Tier C only) ---------------------------------------
__global__ __launch_bounds__(64) void k_softmax(const float* __restrict__ logits,
                                                float* __restrict__ attnT) {
  int bh = blockIdx.x;
  int b = bh / Hh, h = bh % Hh;
  const float* row = logits + (size_t)bh * Nn;
  int t = threadIdx.x;
  float vals[10];
  float m = -1e30f;
#pragma unroll
  for (int i = 0; i < 10; ++i) {
    int n = i * 64 + t;
    vals[i] = (n < Nn) ? row[n] : -1e30f;
    m = fmaxf(m, vals[i]);
  }
#pragma unroll
  for (int off = 32; off; off >>= 1) m = fmaxf(m, __shfl_down(m, off));
  m = __shfl(m, 0);
  float s = 0.f;
#pragma unroll
  for (int i = 0; i < 10; ++i) { vals[i] = __expf(vals[i] - m); s += vals[i]; }
#pragma unroll
  for (int off = 32; off; off >>= 1) s += __shfl_down(s, off);
  float inv = 1.f / __shfl(s, 0);
#pragma unroll
  for (int i = 0; i < 10; ++i) {
    int n = i * 64 + t;
    if (n < Nn) attnT[((size_t)b * Nn + n) * Hh + h] = vals[i] * inv;
  }
}

// ===== k_y3s: fused softmax + attn*x + out-copy ===============================
// 512 blocks x 576 threads. Stats phase: per (b,h) max/sum over all n from
// L2-resident logits (48 threads per h, LDS reduce). Main loop: attn on the
// fly (exp+scale), x read rides out-copy (NT). ypart plain stores.
__global__ __launch_bounds__(576) void k_y3s(const float* __restrict__ x,
                                             const float* __restrict__ logits,
                                             float* __restrict__ ypart,
                                             float* __restrict__ out) {
  int b = blockIdx.x / YSEG, seg = blockIdx.x % YSEG;
  int c4 = threadIdx.x % 192;
  int sub = threadIdx.x / 192;              // 0..2, wave-uniform
  const float* lg = logits + (size_t)b * Hh * Nn;
  __shared__ float red1[576];
  __shared__ float sm_m[Hh], sm_inv[Hh];
  {
    int h = threadIdx.x / 48, j = threadIdx.x % 48;   // 12 x 48 = 576
    float mx = -1e30f;
    for (int n = j; n < Nn; n += 48) mx = fmaxf(mx, lg[h * Nn + n]);
    red1[threadIdx.x] = mx;
    __syncthreads();
    if (j == 0) {
      float mm = red1[h * 48];
      for (int k = 1; k < 48; ++k) mm = fmaxf(mm, red1[h * 48 + k]);
      sm_m[h] = mm;
    }
    __syncthreads();
    float mh = sm_m[h];
    float s = 0.f;
    for (int n = j; n < Nn; n += 48) s += __expf(lg[h * Nn + n] - mh);
    red1[threadIdx.x] = s;
    __syncthreads();
    if (j == 0) {
      float l = 0.f;
      for (int k = 0; k < 48; ++k) l += red1[h * 48 + k];
      sm_inv[h] = 1.f / l;
    }
    __syncthreads();
  }
  float mh[Hh], ih[Hh];
#pragma unroll
  for (int h = 0; h < Hh; ++h) { mh[h] = sm_m[h]; ih[h] = sm_inv[h]; }

  int n0 = seg * Nn / YSEG, n1 = (seg + 1) * Nn / YSEG;
  int len = n1 - n0;
  int a0 = n0 + sub * len / 3, a1 = n0 + (sub + 1) * len / 3;
  float4v acc[Hh];
#pragma unroll
  for (int h = 0; h < Hh; ++h) acc[h] = (float4v){0.f, 0.f, 0.f, 0.f};
  const float4v* x4 = (const float4v*)(x + (size_t)b * Nn * Cc);
  float4v* o4 = (float4v*)(out + (size_t)b * Nn * Cc);
#pragma unroll 4
  for (int n = a0; n < a1; ++n) {
    float4v xv = x4[(size_t)n * 192 + c4];
    if (n)                                    // row 0 belongs to cls (gemm<2>)
      __builtin_nontemporal_store(xv, o4 + (size_t)n * 192 + c4);
#pragma unroll
    for (int h = 0; h < Hh; ++h) {
      float a = __expf(lg[h * Nn + n] - mh[h]) * ih[h];  // uniform load + exp
      acc[h] += a * xv;
    }
  }
  __shared__ float4v red[192][Hh];          // 36,864 B
  if (sub == 2) {
#pragma unroll
    for (int h = 0; h < Hh; ++h) red[c4][h] = acc[h];
  }
  __syncthreads();
  if (sub == 1) {
#pragma unroll
    for (int h = 0; h < Hh; ++h) { acc[h] += red[c4][h]; red[c4][h] = acc[h]; }
  }
  __syncthreads();
  if (sub == 0) {
    float4v* yp = (float4v*)(ypart + ((size_t)(b * YSEG + seg)) * (Hh * Cc));
#pragma unroll
    for (int h = 0; h < Hh; ++h) yp[h * 192 + c4] = acc[h] + red[c4][h];
  }
}

// ----------------- Tier C fallback kernels (previous verified path) -----------
__global__ __launch_bounds__(256) void k_zero(float* __restrict__ y) {
  ((float4*)y)[blockIdx.x * 256 + threadIdx.x] = make_float4(0.f, 0.f, 0.f, 0.f);
}

__global__ __launch_bounds__(192) void k_y_atomic(const float* __restrict__ x,
                                                  const float* __restrict__ attnT,
                                                  float* __restrict__ y) {
  int b = blockIdx.x / YSEG, seg = blockIdx.x % YSEG;
  int n0 = seg * Nn / YSEG, n1 = (seg + 1) * Nn / YSEG;
  int c4 = threadIdx.x;
  float4 acc[Hh];
#pragma unroll
  for (int h = 0; h < Hh; ++h) acc[h] = make_float4(0.f, 0.f, 0.f, 0.f);
  const float4* x4 = (const float4*)(x + (size_t)b * Nn * Cc);
  const float* at = attnT + (size_t)b * Nn * Hh;
#pragma unroll 8
  for (int n = n0; n < n1; ++n) {
    float4 xv = x4[(size_t)n * 192 + c4];
#pragma unroll
    for (int h = 0; h < Hh; ++h) {
      float a = at[n * Hh + h];
      acc[h].x += a * xv.x; acc[h].y += a * xv.y;
      acc[h].z += a * xv.z; acc[h].w += a * xv.w;
    }
  }
  float* yb = y + (size_t)b * Hh * Cc;
#pragma unroll
  for (int h = 0; h < Hh; ++h) {
    float* p = yb + h * Cc + c4 * 4;
    atomicAdd(p + 0, acc[h].x); atomicAdd(p + 1, acc[h].y);
    atomicAdd(p + 2, acc[h].z); atomicAdd(p + 3, acc[h].w);
  }
}

__global__ __launch_bounds__(256) void k_copy(const float* __restrict__ x,
                                              float* __restrict__ out) {
  int idx = blockIdx.x * 256 + threadIdx.x;
  const float4* xi = (const float4*)x;
  float4* oo = (float4*)out;
  for (int i = idx; i < 7077888; i += 262144) {
    int b = i / 110592;
    int r = i - b * 110592;
    size_t off = (size_t)b * 110784 + 192 + r;
    oo[off] = xi[off];
  }
}

extern "C" void kernel_launch(void* const* d_in, const int* in_sizes, int n_in,
                              void* d_out, int out_size, void* d_ws, size_t ws_size,
                              hipStream_t stream) {
  const float* x      = (const float*)d_in[0];
  const float* qkv_w  = (const float*)d_in[1];
  const float* qkv_b  = (const float*)d_in[2];
  const float* proj_w = (const float*)d_in[3];
  const float* proj_b = (const float*)d_in[4];
  float* out = (float*)d_out;
  float* ws = (float*)d_ws;

  unsigned short* rb = (unsigned short*)ws;     // 786,432 bf16
  float* logits = ws + 442368;
  float* attnT  = ws + 885504;
  float* ypart  = ws + 1328640;                 // 4,718,592 floats
  float* cls    = ws + 6047232;                 // 49,152 floats

  const size_t NEED_PART = (size_t)6096384 * 4; // ~24.4 MB

  if (ws_size >= NEED_PART) {
    // Main: 5 dispatches. Fused q+r; fused softmax+y+copy.
    k_rq<<<192, 256, 0, stream>>>(x, qkv_w, qkv_b, rb);
    k_logits<<<Bz * 10, 256, 0, stream>>>(x, rb, logits);
    k_y3s<<<Bz * YSEG, 576, 0, stream>>>(x, logits, ypart, out);
    k_gemm64<1, YSEG><<<192, 256, 0, stream>>>(ypart, qkv_w, qkv_b, cls);
    k_gemm64<2, 1><<<192, 256, 0, stream>>>(cls, proj_w, proj_b, out);
  } else {
    // Tier C: previous verified pipeline (7.87 MB ws).
    float* y     = ws + 1328640;
    float* cls_c = ws + 1918464;
    k_zero<<<576, 256, 0, stream>>>(y);
    k_rq<<<192, 256, 0, stream>>>(x, qkv_w, qkv_b, rb);
    k_logits<<<Bz * 10, 256, 0, stream>>>(x, rb, logits);
    k_softmax<<<Bz * Hh, 64, 0, stream>>>(logits, attnT);
    k_y_atomic<<<Bz * YSEG, 192, 0, stream>>>(x, attnT, y);
    k_gemm64<1, 1><<<192, 256, 0, stream>>>(y, qkv_w, qkv_b, cls_c);
    k_gemm64<2, 1><<<192, 256, 0, stream>>>(cls_c, proj_w, proj_b, out);
    k_copy<<<1024, 256, 0, stream>>>(x, out);
  }
}

// Round 9
// 298.600 us; speedup vs baseline: 1.0428x; 1.0428x over previous
//
#include <hip/hip_runtime.h>

#define Bz 64
#define Nn 577
#define Cc 768
#define Hh 12
#define Dd 64
#define SCALE 0.125f
#define YSEG 8

typedef __attribute__((ext_vector_type(8))) short short8;
typedef __attribute__((ext_vector_type(4))) float float4v;

__device__ __forceinline__ unsigned short bf16rne(float f) {
  unsigned u = __float_as_uint(f);
  u += 0x7FFFu + ((u >> 16) & 1u);
  return (unsigned short)(u >> 16);
}

__device__ __forceinline__ short8 cvt8(float4 a, float4 b) {
  short8 v;
  v[0] = (short)bf16rne(a.x); v[1] = (short)bf16rne(a.y);
  v[2] = (short)bf16rne(a.z); v[3] = (short)bf16rne(a.w);
  v[4] = (short)bf16rne(b.x); v[5] = (short)bf16rne(b.y);
  v[6] = (short)bf16rne(b.z); v[7] = (short)bf16rne(b.w);
  return v;
}

__device__ __forceinline__ short8 cvt8v(float4v a, float4v b) {
  short8 v;
  v[0] = (short)bf16rne(a[0]); v[1] = (short)bf16rne(a[1]);
  v[2] = (short)bf16rne(a[2]); v[3] = (short)bf16rne(a[3]);
  v[4] = (short)bf16rne(b[0]); v[5] = (short)bf16rne(b[1]);
  v[6] = (short)bf16rne(b[2]); v[7] = (short)bf16rne(b[3]);
  return v;
}

// ws layout (float units), main tier (needs ~24.4 MB):
//   rb     @ 0        : 786,432 bf16 (393,216 float slots) [B][24 s][4 q][16 m=h][8 j]
//   qf     @ 393216   : [B][C] fp32
//   logits @ 442368   : [B][H][N] fp32
//   attnT  @ 885504   : [B][N][H] fp32
//   ypart  @ 1328640  : [B][YSEG][H][C] fp32 (plain stores, summed in gemm<1>)
//   cls    @ 6047232  : [B][C] fp32
// Tier C (old, needs 7.87 MB): y @ 1328640 (atomic), cls @ 1918464.

// ============ k_gemm64: C(64 x 768) = A(64 x 768) @ W_rows^T + bias ===========
// MODE 0: q   = X0 @ Wq^T      (A row stride Nn*Cc;  W rows j;        out q)
// MODE 1: cls = Y_h @ Wv^T     (A = ypart[b][seg][h=jt>>2]; SEGS summed; W rows 2C+j)
// MODE 2: out0 = cls @ projW^T (A row stride Cc;     W rows j;        out row0)
template <int MODE, int SEGS>
__global__ __launch_bounds__(256) void k_gemm64(const float* __restrict__ A,
                                                const float* __restrict__ W,
                                                const float* __restrict__ bias,
                                                float* __restrict__ out) {
  int tile = blockIdx.x;            // 0..191
  int jt = tile % 48, bt = tile / 48;
  int wave = threadIdx.x >> 6, lane = threadIdx.x & 63;
  int m = lane & 15, quad = lane >> 4;
  int brow = bt * 16 + m;
  int jrow = jt * 16 + m;
  size_t aoff;
  if (MODE == 0)      aoff = (size_t)brow * (Nn * Cc);
  else if (MODE == 1) aoff = (size_t)brow * (SEGS * Hh * Cc) + (size_t)(jt >> 2) * Cc;
  else                aoff = (size_t)brow * Cc;
  size_t woff = (MODE == 1) ? (size_t)(2 * Cc + jrow) * Cc : (size_t)jrow * Cc;
  const float4v* Ap = (const float4v*)(A + aoff) + wave * 48 + quad * 2;
  const float4v* Wp = (const float4v*)(W + woff) + wave * 48 + quad * 2;
  float4v acc = {0.f, 0.f, 0.f, 0.f};
#pragma unroll
  for (int s = 0; s < 6; ++s) {
    float4v a0, a1;
    if (MODE == 1 && SEGS > 1) {
      a0 = (float4v){0.f, 0.f, 0.f, 0.f};
      a1 = a0;
#pragma unroll
      for (int seg = 0; seg < SEGS; ++seg) {
        a0 += Ap[seg * 2304 + s * 8];      // 2304 = H*C/4 float4 per seg
        a1 += Ap[seg * 2304 + s * 8 + 1];
      }
    } else {
      a0 = Ap[s * 8]; a1 = Ap[s * 8 + 1];
    }
    float4v w0 = Wp[s * 8], w1 = Wp[s * 8 + 1];
    acc = __builtin_amdgcn_mfma_f32_16x16x32_bf16(cvt8v(a0, a1), cvt8v(w0, w1),
                                                  acc, 0, 0, 0);
  }
  __shared__ float red[4][64][4];
#pragma unroll
  for (int reg = 0; reg < 4; ++reg) red[wave][lane][reg] = acc[reg];
  __syncthreads();
  if (wave == 0) {
#pragma unroll
    for (int reg = 0; reg < 4; ++reg) {
      float v = red[0][lane][reg] + red[1][lane][reg] +
                red[2][lane][reg] + red[3][lane][reg];
      int j = jt * 16 + m;
      int bb = bt * 16 + quad * 4 + reg;
      float bv = (MODE == 1) ? bias[2 * Cc + j] : bias[j];
      if (MODE == 2) out[(size_t)bb * (Nn * Cc) + j] = v + bv;
      else           out[(size_t)bb * Cc + j] = v + bv;
    }
  }
}

// ====== k_r: rb[b][s][q][h][j] = bf16(SCALE * sum_d q[b,h,d] * Wk[h,d,c]) =====
__global__ __launch_bounds__(256) void k_r(const float* __restrict__ qf,
                                           const float* __restrict__ qkv_w,
                                           unsigned short* __restrict__ rb) {
  int h = blockIdx.x % Hh, bg = blockIdx.x / Hh;
  int t = threadIdx.x;
  __shared__ float qs2[Dd][8];
  for (int idx = t; idx < 512; idx += 256) {
    int bb = idx >> 6, d = idx & 63;
    qs2[d][bb] = qf[(size_t)(bg * 8 + bb) * Cc + h * Dd + d];
  }
  __syncthreads();
  float acc[8][3];
#pragma unroll
  for (int bb = 0; bb < 8; ++bb)
#pragma unroll
    for (int i = 0; i < 3; ++i) acc[bb][i] = 0.f;
  const float* wk = qkv_w + (size_t)(Cc + h * Dd) * Cc;
  for (int d = 0; d < Dd; ++d) {
    float w0 = wk[(size_t)d * Cc + t];
    float w1 = wk[(size_t)d * Cc + t + 256];
    float w2 = wk[(size_t)d * Cc + t + 512];
    float4 qa = *(const float4*)&qs2[d][0];
    float4 qb = *(const float4*)&qs2[d][4];
    float qv[8] = {qa.x, qa.y, qa.z, qa.w, qb.x, qb.y, qb.z, qb.w};
#pragma unroll
    for (int bb = 0; bb < 8; ++bb) {
      acc[bb][0] += qv[bb] * w0;
      acc[bb][1] += qv[bb] * w1;
      acc[bb][2] += qv[bb] * w2;
    }
  }
#pragma unroll
  for (int bb = 0; bb < 8; ++bb) {
    size_t base = (size_t)(bg * 8 + bb) * 12288 + h * 8;
#pragma unroll
    for (int i = 0; i < 3; ++i) {
      int c = t + i * 256;
      int s = c >> 5, qq = (c >> 3) & 3, j = c & 7;
      rb[base + s * 512 + qq * 128 + j] = bf16rne(acc[bb][i] * SCALE);
    }
  }
}

// ===== k_logits: MFMA straight from global (no LDS, no barriers) ==============
// fp32 x loads + inline bf16 cvt (each x row is read exactly once; x stays L3).
__global__ __launch_bounds__(256) void k_logits(const float* __restrict__ x,
                                                const unsigned short* __restrict__ rb,
                                                float* __restrict__ logits) {
  int b = blockIdx.x / 10, tile = blockIdx.x % 10;
  int wave = threadIdx.x >> 6, lane = threadIdx.x & 63;
  int m = lane & 15, quad = lane >> 4;
  int n = tile * 64 + wave * 16 + m;
  int nc = n > 576 ? 576 : n;
  const short8* ag = (const short8*)(rb + (size_t)b * 12288);
  const float4* xg = (const float4*)(x + (size_t)b * Nn * Cc) + (size_t)nc * 192 + quad * 2;
  float4v acc = {0.f, 0.f, 0.f, 0.f};
#pragma unroll 8
  for (int s = 0; s < 24; ++s) {
    short8 a = ag[s * 64 + quad * 16 + m];
    float4 f0 = xg[s * 8], f1 = xg[s * 8 + 1];
    acc = __builtin_amdgcn_mfma_f32_16x16x32_bf16(a, cvt8(f0, f1), acc, 0, 0, 0);
  }
  if (n < Nn) {
#pragma unroll
    for (int reg = 0; reg < 4; ++reg) {
      int hh = quad * 4 + reg;
      if (hh < Hh) logits[((size_t)b * Hh + hh) * Nn + n] = acc[reg];
    }
  }
}

// ---------------- softmax over n, write transposed attnT[b][n][h] -------------
__global__ __launch_bounds__(64) void k_softmax(const float* __restrict__ logits,
                                                float* __restrict__ attnT) {
  int bh = blockIdx.x;
  int b = bh / Hh, h = bh % Hh;
  const float* row = logits + (size_t)bh * Nn;
  int t = threadIdx.x;
  float vals[10];
  float m = -1e30f;
#pragma unroll
  for (int i = 0; i < 10; ++i) {
    int n = i * 64 + t;
    vals[i] = (n < Nn) ? row[n] : -1e30f;
    m = fmaxf(m, vals[i]);
  }
#pragma unroll
  for (int off = 32; off; off >>= 1) m = fmaxf(m, __shfl_down(m, off));
  m = __shfl(m, 0);
  float s = 0.f;
#pragma unroll
  for (int i = 0; i < 10; ++i) { vals[i] = __expf(vals[i] - m); s += vals[i]; }
#pragma unroll
  for (int off = 32; off; off >>= 1) s += __shfl_down(s, off);
  float inv = 1.f / __shfl(s, 0);
#pragma unroll
  for (int i = 0; i < 10; ++i) {
    int n = i * 64 + t;
    if (n < Nn) attnT[((size_t)b * Nn + n) * Hh + h] = vals[i] * inv;
  }
}

// ===== k_y3c: ypart[b,seg,h,c] = sum attn * x  AND  out[:,1:,:] = x[:,1:,:] ===
// 512 blocks x 576 threads (9 waves). Each (b,n,c4) of x is loaded by exactly
// one thread -> the out-copy rides the existing read for free.
__global__ __launch_bounds__(576) void k_y3c(const float* __restrict__ x,
                                             const float* __restrict__ attnT,
                                             float* __restrict__ ypart,
                                             float* __restrict__ out) {
  int b = blockIdx.x / YSEG, seg = blockIdx.x % YSEG;
  int c4 = threadIdx.x % 192;
  int sub = threadIdx.x / 192;              // 0..2, wave-uniform (192 = 3 waves)
  int n0 = seg * Nn / YSEG, n1 = (seg + 1) * Nn / YSEG;
  int len = n1 - n0;
  int a0 = n0 + sub * len / 3, a1 = n0 + (sub + 1) * len / 3;
  float4v acc[Hh];
#pragma unroll
  for (int h = 0; h < Hh; ++h) acc[h] = (float4v){0.f, 0.f, 0.f, 0.f};
  const float4v* x4 = (const float4v*)(x + (size_t)b * Nn * Cc);
  float4v* o4 = (float4v*)(out + (size_t)b * Nn * Cc);
  const float* at = attnT + (size_t)b * Nn * Hh;
#pragma unroll 8
  for (int n = a0; n < a1; ++n) {
    float4v xv = x4[(size_t)n * 192 + c4];
    if (n)                                    // row 0 belongs to cls (gemm<2>)
      __builtin_nontemporal_store(xv, o4 + (size_t)n * 192 + c4);
#pragma unroll
    for (int h = 0; h < Hh; ++h) acc[h] += at[n * Hh + h] * xv;  // at: s_load
  }
  __shared__ float4v red[192][Hh];          // 36,864 B
  if (sub == 2) {
#pragma unroll
    for (int h = 0; h < Hh; ++h) red[c4][h] = acc[h];
  }
  __syncthreads();
  if (sub == 1) {
#pragma unroll
    for (int h = 0; h < Hh; ++h) { acc[h] += red[c4][h]; red[c4][h] = acc[h]; }
  }
  __syncthreads();
  if (sub == 0) {
    float4v* yp = (float4v*)(ypart + ((size_t)(b * YSEG + seg)) * (Hh * Cc));
#pragma unroll
    for (int h = 0; h < Hh; ++h) yp[h * 192 + c4] = acc[h] + red[c4][h];
  }
}

// ----------------- Tier C fallback kernels (previous verified path) -----------
__global__ __launch_bounds__(256) void k_zero(float* __restrict__ y) {
  ((float4*)y)[blockIdx.x * 256 + threadIdx.x] = make_float4(0.f, 0.f, 0.f, 0.f);
}

__global__ __launch_bounds__(192) void k_y_atomic(const float* __restrict__ x,
                                                  const float* __restrict__ attnT,
                                                  float* __restrict__ y) {
  int b = blockIdx.x / YSEG, seg = blockIdx.x % YSEG;
  int n0 = seg * Nn / YSEG, n1 = (seg + 1) * Nn / YSEG;
  int c4 = threadIdx.x;
  float4 acc[Hh];
#pragma unroll
  for (int h = 0; h < Hh; ++h) acc[h] = make_float4(0.f, 0.f, 0.f, 0.f);
  const float4* x4 = (const float4*)(x + (size_t)b * Nn * Cc);
  const float* at = attnT + (size_t)b * Nn * Hh;
#pragma unroll 8
  for (int n = n0; n < n1; ++n) {
    float4 xv = x4[(size_t)n * 192 + c4];
#pragma unroll
    for (int h = 0; h < Hh; ++h) {
      float a = at[n * Hh + h];
      acc[h].x += a * xv.x; acc[h].y += a * xv.y;
      acc[h].z += a * xv.z; acc[h].w += a * xv.w;
    }
  }
  float* yb = y + (size_t)b * Hh * Cc;
#pragma unroll
  for (int h = 0; h < Hh; ++h) {
    float* p = yb + h * Cc + c4 * 4;
    atomicAdd(p + 0, acc[h].x); atomicAdd(p + 1, acc[h].y);
    atomicAdd(p + 2, acc[h].z); atomicAdd(p + 3, acc[h].w);
  }
}

__global__ __launch_bounds__(256) void k_copy(const float* __restrict__ x,
                                              float* __restrict__ out) {
  int idx = blockIdx.x * 256 + threadIdx.x;
  const float4* xi = (const float4*)x;
  float4* oo = (float4*)out;
  for (int i = idx; i < 7077888; i += 262144) {
    int b = i / 110592;
    int r = i - b * 110592;
    size_t off = (size_t)b * 110784 + 192 + r;
    oo[off] = xi[off];
  }
}

extern "C" void kernel_launch(void* const* d_in, const int* in_sizes, int n_in,
                              void* d_out, int out_size, void* d_ws, size_t ws_size,
                              hipStream_t stream) {
  const float* x      = (const float*)d_in[0];
  const float* qkv_w  = (const float*)d_in[1];
  const float* qkv_b  = (const float*)d_in[2];
  const float* proj_w = (const float*)d_in[3];
  const float* proj_b = (const float*)d_in[4];
  float* out = (float*)d_out;
  float* ws = (float*)d_ws;

  unsigned short* rb = (unsigned short*)ws;     // 786,432 bf16
  float* qf     = ws + 393216;
  float* logits = ws + 442368;
  float* attnT  = ws + 885504;
  float* ypart  = ws + 1328640;                 // 4,718,592 floats
  float* cls    = ws + 6047232;                 // 49,152 floats

  const size_t NEED_PART = (size_t)6096384 * 4; // ~24.4 MB

  if (ws_size >= NEED_PART) {
    // Main (round-6 verified best): fp32 logits; attn*x with fused out-copy;
    // partial-buffer y summed in gemm<1>.
    k_gemm64<0, 1><<<192, 256, 0, stream>>>(x, qkv_w, qkv_b, qf);
    k_r<<<96, 256, 0, stream>>>(qf, qkv_w, rb);
    k_logits<<<Bz * 10, 256, 0, stream>>>(x, rb, logits);
    k_softmax<<<Bz * Hh, 64, 0, stream>>>(logits, attnT);
    k_y3c<<<Bz * YSEG, 576, 0, stream>>>(x, attnT, ypart, out);
    k_gemm64<1, YSEG><<<192, 256, 0, stream>>>(ypart, qkv_w, qkv_b, cls);
    k_gemm64<2, 1><<<192, 256, 0, stream>>>(cls, proj_w, proj_b, out);
  } else {
    // Tier C: previous verified pipeline (7.87 MB ws).
    float* y     = ws + 1328640;
    float* cls_c = ws + 1918464;
    k_zero<<<576, 256, 0, stream>>>(y);
    k_gemm64<0, 1><<<192, 256, 0, stream>>>(x, qkv_w, qkv_b, qf);
    k_r<<<96, 256, 0, stream>>>(qf, qkv_w, rb);
    k_logits<<<Bz * 10, 256, 0, stream>>>(x, rb, logits);
    k_softmax<<<Bz * Hh, 64, 0, stream>>>(logits, attnT);
    k_y_atomic<<<Bz * YSEG, 192, 0, stream>>>(x, attnT, y);
    k_gemm64<1, 1><<<192, 256, 0, stream>>>(y, qkv_w, qkv_b, cls_c);
    k_gemm64<2, 1><<<192, 256, 0, stream>>>(cls_c, proj_w, proj_b, out);
  }
}

// Round 10
// 296.797 us; speedup vs baseline: 1.0492x; 1.0061x over previous
//
#include <hip/hip_runtime.h>

#define Bz 64
#define Nn 577
#define Cc 768
#define Hh 12
#define Dd 64
#define SCALE 0.125f
#define YSEG 8

typedef __attribute__((ext_vector_type(8))) short short8;
typedef __attribute__((ext_vector_type(4))) float float4v;

__device__ __forceinline__ unsigned short bf16rne(float f) {
  unsigned u = __float_as_uint(f);
  u += 0x7FFFu + ((u >> 16) & 1u);
  return (unsigned short)(u >> 16);
}

__device__ __forceinline__ short8 cvt8(float4 a, float4 b) {
  short8 v;
  v[0] = (short)bf16rne(a.x); v[1] = (short)bf16rne(a.y);
  v[2] = (short)bf16rne(a.z); v[3] = (short)bf16rne(a.w);
  v[4] = (short)bf16rne(b.x); v[5] = (short)bf16rne(b.y);
  v[6] = (short)bf16rne(b.z); v[7] = (short)bf16rne(b.w);
  return v;
}

__device__ __forceinline__ short8 cvt8v(float4v a, float4v b) {
  short8 v;
  v[0] = (short)bf16rne(a[0]); v[1] = (short)bf16rne(a[1]);
  v[2] = (short)bf16rne(a[2]); v[3] = (short)bf16rne(a[3]);
  v[4] = (short)bf16rne(b[0]); v[5] = (short)bf16rne(b[1]);
  v[6] = (short)bf16rne(b[2]); v[7] = (short)bf16rne(b[3]);
  return v;
}

// ws layout (float units), main tier (needs ~24.44 MB):
//   rb     @ 0        : 786,432 bf16 (393,216 float slots)
//   qf     @ 393216   : [B][C] fp32
//   logits @ 442368   : [B][H][N] fp32 (Tier C only)
//   attnT  @ 885504   : [B][N][H] fp32 (Tier C only)
//   ypart  @ 1328640  : [B][YSEG][H][C] fp32 (UNNORMALIZED weighted p-sums)
//   cls    @ 6047232  : [B][C] fp32
//   mstat  @ 6096384  : [B][YSEG][H] fp32 (seg-local max)
//   lstat  @ 6102528  : [B][YSEG][H] fp32 (seg-local exp-sum)  end @ 6108672

// ============ k_gemm64: C(64 x 768) = A(64 x 768) @ W_rows^T + bias ===========
// MODE 0: q   = X0 @ Wq^T
// MODE 1: cls = V_h @ Wv^T ; SEGS summed; WTD: flash-weighted seg combine
// MODE 2: out0 = cls @ projW^T
template <int MODE, int SEGS, int WTD = 0>
__global__ __launch_bounds__(256) void k_gemm64(const float* __restrict__ A,
                                                const float* __restrict__ W,
                                                const float* __restrict__ bias,
                                                float* __restrict__ out,
                                                const float* __restrict__ mstat,
                                                const float* __restrict__ lstat) {
  int tile = blockIdx.x;            // 0..191
  int jt = tile % 48, bt = tile / 48;
  int wave = threadIdx.x >> 6, lane = threadIdx.x & 63;
  int m = lane & 15, quad = lane >> 4;
  int brow = bt * 16 + m;
  int jrow = jt * 16 + m;
  size_t aoff;
  if (MODE == 0)      aoff = (size_t)brow * (Nn * Cc);
  else if (MODE == 1) aoff = (size_t)brow * (SEGS * Hh * Cc) + (size_t)(jt >> 2) * Cc;
  else                aoff = (size_t)brow * Cc;
  size_t woff = (MODE == 1) ? (size_t)(2 * Cc + jrow) * Cc : (size_t)jrow * Cc;
  const float4v* Ap = (const float4v*)(A + aoff) + wave * 48 + quad * 2;
  const float4v* Wp = (const float4v*)(W + woff) + wave * 48 + quad * 2;
  float wseg[SEGS > 1 ? SEGS : 1];
  float invL = 1.f;
  if (MODE == 1 && WTD) {
    int h = jt >> 2;
    float M = -1e30f;
#pragma unroll
    for (int s = 0; s < SEGS; ++s)
      M = fmaxf(M, mstat[((size_t)brow * YSEG + s) * Hh + h]);
    float L = 0.f;
#pragma unroll
    for (int s = 0; s < SEGS; ++s) {
      wseg[s] = __expf(mstat[((size_t)brow * YSEG + s) * Hh + h] - M);
      L += wseg[s] * lstat[((size_t)brow * YSEG + s) * Hh + h];
    }
    invL = 1.f / L;
  }
  float4v acc = {0.f, 0.f, 0.f, 0.f};
#pragma unroll
  for (int s = 0; s < 6; ++s) {
    float4v a0, a1;
    if (MODE == 1 && SEGS > 1) {
      a0 = (float4v){0.f, 0.f, 0.f, 0.f};
      a1 = a0;
#pragma unroll
      for (int seg = 0; seg < SEGS; ++seg) {
        if (WTD) {
          a0 += wseg[seg] * Ap[seg * 2304 + s * 8];
          a1 += wseg[seg] * Ap[seg * 2304 + s * 8 + 1];
        } else {
          a0 += Ap[seg * 2304 + s * 8];
          a1 += Ap[seg * 2304 + s * 8 + 1];
        }
      }
      if (WTD) { a0 *= invL; a1 *= invL; }
    } else {
      a0 = Ap[s * 8]; a1 = Ap[s * 8 + 1];
    }
    float4v w0 = Wp[s * 8], w1 = Wp[s * 8 + 1];
    acc = __builtin_amdgcn_mfma_f32_16x16x32_bf16(cvt8v(a0, a1), cvt8v(w0, w1),
                                                  acc, 0, 0, 0);
  }
  __shared__ float red[4][64][4];
#pragma unroll
  for (int reg = 0; reg < 4; ++reg) red[wave][lane][reg] = acc[reg];
  __syncthreads();
  if (wave == 0) {
#pragma unroll
    for (int reg = 0; reg < 4; ++reg) {
      float v = red[0][lane][reg] + red[1][lane][reg] +
                red[2][lane][reg] + red[3][lane][reg];
      int j = jt * 16 + m;
      int bb = bt * 16 + quad * 4 + reg;
      float bv = (MODE == 1) ? bias[2 * Cc + j] : bias[j];
      if (MODE == 2) out[(size_t)bb * (Nn * Cc) + j] = v + bv;
      else           out[(size_t)bb * Cc + j] = v + bv;
    }
  }
}

// ====== k_r: rb[b][s][q][h][j] = bf16(SCALE * sum_d q[b,h,d] * Wk[h,d,c]) =====
__global__ __launch_bounds__(256) void k_r(const float* __restrict__ qf,
                                           const float* __restrict__ qkv_w,
                                           unsigned short* __restrict__ rb) {
  int h = blockIdx.x % Hh, bg = blockIdx.x / Hh;
  int t = threadIdx.x;
  __shared__ float qs2[Dd][8];
  for (int idx = t; idx < 512; idx += 256) {
    int bb = idx >> 6, d = idx & 63;
    qs2[d][bb] = qf[(size_t)(bg * 8 + bb) * Cc + h * Dd + d];
  }
  __syncthreads();
  float acc[8][3];
#pragma unroll
  for (int bb = 0; bb < 8; ++bb)
#pragma unroll
    for (int i = 0; i < 3; ++i) acc[bb][i] = 0.f;
  const float* wk = qkv_w + (size_t)(Cc + h * Dd) * Cc;
  for (int d = 0; d < Dd; ++d) {
    float w0 = wk[(size_t)d * Cc + t];
    float w1 = wk[(size_t)d * Cc + t + 256];
    float w2 = wk[(size_t)d * Cc + t + 512];
    float4 qa = *(const float4*)&qs2[d][0];
    float4 qb = *(const float4*)&qs2[d][4];
    float qv[8] = {qa.x, qa.y, qa.z, qa.w, qb.x, qb.y, qb.z, qb.w};
#pragma unroll
    for (int bb = 0; bb < 8; ++bb) {
      acc[bb][0] += qv[bb] * w0;
      acc[bb][1] += qv[bb] * w1;
      acc[bb][2] += qv[bb] * w2;
    }
  }
#pragma unroll
  for (int bb = 0; bb < 8; ++bb) {
    size_t base = (size_t)(bg * 8 + bb) * 12288 + h * 8;
#pragma unroll
    for (int i = 0; i < 3; ++i) {
      int c = t + i * 256;
      int s = c >> 5, qq = (c >> 3) & 3, j = c & 7;
      rb[base + s * 512 + qq * 128 + j] = bf16rne(acc[bb][i] * SCALE);
    }
  }
}

// ===== k_flash: per (b,seg): MFMA logits -> seg-local softmax -> p*x accum ====
// Phase 1 (waves 0-4): k_logits' proven MFMA body over this seg's rows; the NT
//   out-copy rides the x load (each row loaded once per block). Logits -> LDS.
// Phase 2: seg-local (m_s, l_s) per h; p = exp(lg - m_s) in LDS (not in c4 loop).
// Phase 3: k_y3c's proven accumulate + 3-sub LDS reduce; x rows re-read L1/L2-hot.
// Stores UNNORMALIZED ypart + stats; gemm<1,WTD> combines segs exactly.
__global__ __launch_bounds__(576) void k_flash(const float* __restrict__ x,
                                               const unsigned short* __restrict__ rb,
                                               float* __restrict__ ypart,
                                               float* __restrict__ mstat,
                                               float* __restrict__ lstat,
                                               float* __restrict__ out) {
  int b = blockIdx.x / YSEG, seg = blockIdx.x % YSEG;
  int n0 = seg * Nn / YSEG, n1 = (seg + 1) * Nn / YSEG;
  int len = n1 - n0;                         // 72 or 73
  int tid = threadIdx.x;
  int wave = tid >> 6, lane = tid & 63;
  int m = lane & 15, quad = lane >> 4;
  __shared__ float lgs[80][13];              // padded; logits then p
  __shared__ float sm_m[Hh];

  if (wave < 5) {                            // phase 1: 80 rows >= len
    int nl = wave * 16 + m;
    int n = n0 + nl;
    int nc = n < n1 ? n : (n1 - 1);          // clamp duplicate loads
    bool owns = (n > 0 && n < n1);           // row 0 belongs to gemm<2>
    const short8* ag = (const short8*)(rb + (size_t)b * 12288);
    const float4v* xg = (const float4v*)(x + (size_t)b * Nn * Cc) + (size_t)nc * 192 + quad * 2;
    float4v* og = (float4v*)(out + (size_t)b * Nn * Cc) + (size_t)nc * 192 + quad * 2;
    float4v acc = {0.f, 0.f, 0.f, 0.f};
#pragma unroll 8
    for (int s = 0; s < 24; ++s) {
      short8 a = ag[s * 64 + quad * 16 + m];
      float4v f0 = xg[s * 8], f1 = xg[s * 8 + 1];
      if (owns) {
        __builtin_nontemporal_store(f0, og + s * 8);
        __builtin_nontemporal_store(f1, og + s * 8 + 1);
      }
      acc = __builtin_amdgcn_mfma_f32_16x16x32_bf16(a, cvt8v(f0, f1), acc, 0, 0, 0);
    }
    if (nl < len) {
#pragma unroll
      for (int reg = 0; reg < 4; ++reg) {
        int hh = quad * 4 + reg;
        if (hh < Hh) lgs[nl][hh] = acc[reg];
      }
    }
  }
  __syncthreads();

  if (tid < 192) {                           // phase 2: 12 h x 16 lanes
    int h = tid >> 4, j = tid & 15;
    float mx = -1e30f;
    for (int nl = j; nl < len; nl += 16) mx = fmaxf(mx, lgs[nl][h]);
#pragma unroll
    for (int off = 8; off; off >>= 1) mx = fmaxf(mx, __shfl_down(mx, off, 16));
    mx = __shfl(mx, (tid & 48), 64);         // broadcast group leader (lane j=0)
    float s = 0.f;
    for (int nl = j; nl < len; nl += 16) s += __expf(lgs[nl][h] - mx);
#pragma unroll
    for (int off = 8; off; off >>= 1) s += __shfl_down(s, off, 16);
    if (j == 0) {
      sm_m[h] = mx;
      mstat[((size_t)b * YSEG + seg) * Hh + h] = mx;
      lstat[((size_t)b * YSEG + seg) * Hh + h] = s;
    }
  }
  __syncthreads();
  for (int i = tid; i < len * Hh; i += 576) { // phase 2b: p = exp(lg - m)
    int nl = i / Hh, h = i - nl * Hh;
    lgs[nl][h] = __expf(lgs[nl][h] - sm_m[h]);
  }
  __syncthreads();

  // phase 3: proven k_y3c structure (3 subs x 192 c4), weights from LDS
  int c4 = tid % 192;
  int sub = tid / 192;
  int a0 = sub * len / 3, a1 = (sub + 1) * len / 3;   // local row range
  float4v acc2[Hh];
#pragma unroll
  for (int h = 0; h < Hh; ++h) acc2[h] = (float4v){0.f, 0.f, 0.f, 0.f};
  const float4v* x4 = (const float4v*)(x + (size_t)b * Nn * Cc);
#pragma unroll 4
  for (int nl = a0; nl < a1; ++nl) {
    float4v xv = x4[(size_t)(n0 + nl) * 192 + c4];    // L1/L2-hot re-read
#pragma unroll
    for (int h = 0; h < Hh; ++h) acc2[h] += lgs[nl][h] * xv;  // LDS broadcast
  }
  __shared__ float4v red[192][Hh];           // 36,864 B
  if (sub == 2) {
#pragma unroll
    for (int h = 0; h < Hh; ++h) red[c4][h] = acc2[h];
  }
  __syncthreads();
  if (sub == 1) {
#pragma unroll
    for (int h = 0; h < Hh; ++h) { acc2[h] += red[c4][h]; red[c4][h] = acc2[h]; }
  }
  __syncthreads();
  if (sub == 0) {
    float4v* yp = (float4v*)(ypart + ((size_t)(b * YSEG + seg)) * (Hh * Cc));
#pragma unroll
    for (int h = 0; h < Hh; ++h) yp[h * 192 + c4] = acc2[h] + red[c4][h];
  }
}

// ----------------- Tier C fallback kernels (verified legacy path) -------------
__global__ __launch_bounds__(256) void k_logits(const float* __restrict__ x,
                                                const unsigned short* __restrict__ rb,
                                                float* __restrict__ logits) {
  int b = blockIdx.x / 10, tile = blockIdx.x % 10;
  int wave = threadIdx.x >> 6, lane = threadIdx.x & 63;
  int m = lane & 15, quad = lane >> 4;
  int n = tile * 64 + wave * 16 + m;
  int nc = n > 576 ? 576 : n;
  const short8* ag = (const short8*)(rb + (size_t)b * 12288);
  const float4* xg = (const float4*)(x + (size_t)b * Nn * Cc) + (size_t)nc * 192 + quad * 2;
  float4v acc = {0.f, 0.f, 0.f, 0.f};
#pragma unroll 8
  for (int s = 0; s < 24; ++s) {
    short8 a = ag[s * 64 + quad * 16 + m];
    float4 f0 = xg[s * 8], f1 = xg[s * 8 + 1];
    acc = __builtin_amdgcn_mfma_f32_16x16x32_bf16(a, cvt8(f0, f1), acc, 0, 0, 0);
  }
  if (n < Nn) {
#pragma unroll
    for (int reg = 0; reg < 4; ++reg) {
      int hh = quad * 4 + reg;
      if (hh < Hh) logits[((size_t)b * Hh + hh) * Nn + n] = acc[reg];
    }
  }
}

__global__ __launch_bounds__(64) void k_softmax(const float* __restrict__ logits,
                                                float* __restrict__ attnT) {
  int bh = blockIdx.x;
  int b = bh / Hh, h = bh % Hh;
  const float* row = logits + (size_t)bh * Nn;
  int t = threadIdx.x;
  float vals[10];
  float m = -1e30f;
#pragma unroll
  for (int i = 0; i < 10; ++i) {
    int n = i * 64 + t;
    vals[i] = (n < Nn) ? row[n] : -1e30f;
    m = fmaxf(m, vals[i]);
  }
#pragma unroll
  for (int off = 32; off; off >>= 1) m = fmaxf(m, __shfl_down(m, off));
  m = __shfl(m, 0);
  float s = 0.f;
#pragma unroll
  for (int i = 0; i < 10; ++i) { vals[i] = __expf(vals[i] - m); s += vals[i]; }
#pragma unroll
  for (int off = 32; off; off >>= 1) s += __shfl_down(s, off);
  float inv = 1.f / __shfl(s, 0);
#pragma unroll
  for (int i = 0; i < 10; ++i) {
    int n = i * 64 + t;
    if (n < Nn) attnT[((size_t)b * Nn + n) * Hh + h] = vals[i] * inv;
  }
}

__global__ __launch_bounds__(256) void k_zero(float* __restrict__ y) {
  ((float4*)y)[blockIdx.x * 256 + threadIdx.x] = make_float4(0.f, 0.f, 0.f, 0.f);
}

__global__ __launch_bounds__(192) void k_y_atomic(const float* __restrict__ x,
                                                  const float* __restrict__ attnT,
                                                  float* __restrict__ y) {
  int b = blockIdx.x / YSEG, seg = blockIdx.x % YSEG;
  int n0 = seg * Nn / YSEG, n1 = (seg + 1) * Nn / YSEG;
  int c4 = threadIdx.x;
  float4 acc[Hh];
#pragma unroll
  for (int h = 0; h < Hh; ++h) acc[h] = make_float4(0.f, 0.f, 0.f, 0.f);
  const float4* x4 = (const float4*)(x + (size_t)b * Nn * Cc);
  const float* at = attnT + (size_t)b * Nn * Hh;
#pragma unroll 8
  for (int n = n0; n < n1; ++n) {
    float4 xv = x4[(size_t)n * 192 + c4];
#pragma unroll
    for (int h = 0; h < Hh; ++h) {
      float a = at[n * Hh + h];
      acc[h].x += a * xv.x; acc[h].y += a * xv.y;
      acc[h].z += a * xv.z; acc[h].w += a * xv.w;
    }
  }
  float* yb = y + (size_t)b * Hh * Cc;
#pragma unroll
  for (int h = 0; h < Hh; ++h) {
    float* p = yb + h * Cc + c4 * 4;
    atomicAdd(p + 0, acc[h].x); atomicAdd(p + 1, acc[h].y);
    atomicAdd(p + 2, acc[h].z); atomicAdd(p + 3, acc[h].w);
  }
}

__global__ __launch_bounds__(256) void k_copy(const float* __restrict__ x,
                                              float* __restrict__ out) {
  int idx = blockIdx.x * 256 + threadIdx.x;
  const float4* xi = (const float4*)x;
  float4* oo = (float4*)out;
  for (int i = idx; i < 7077888; i += 262144) {
    int b = i / 110592;
    int r = i - b * 110592;
    size_t off = (size_t)b * 110784 + 192 + r;
    oo[off] = xi[off];
  }
}

extern "C" void kernel_launch(void* const* d_in, const int* in_sizes, int n_in,
                              void* d_out, int out_size, void* d_ws, size_t ws_size,
                              hipStream_t stream) {
  const float* x      = (const float*)d_in[0];
  const float* qkv_w  = (const float*)d_in[1];
  const float* qkv_b  = (const float*)d_in[2];
  const float* proj_w = (const float*)d_in[3];
  const float* proj_b = (const float*)d_in[4];
  float* out = (float*)d_out;
  float* ws = (float*)d_ws;

  unsigned short* rb = (unsigned short*)ws;     // 786,432 bf16
  float* qf     = ws + 393216;
  float* logits = ws + 442368;
  float* attnT  = ws + 885504;
  float* ypart  = ws + 1328640;                 // 4,718,592 floats
  float* cls    = ws + 6047232;                 // 49,152 floats
  float* mstat  = ws + 6096384;                 // 6,144 floats
  float* lstat  = ws + 6102528;                 // 6,144 floats

  const size_t NEED_FLASH = (size_t)6108672 * 4;  // ~24.44 MB

  if (ws_size >= NEED_FLASH) {
    // Main: 5 dispatches, single full x traversal in k_flash.
    k_gemm64<0, 1><<<192, 256, 0, stream>>>(x, qkv_w, qkv_b, qf, nullptr, nullptr);
    k_r<<<96, 256, 0, stream>>>(qf, qkv_w, rb);
    k_flash<<<Bz * YSEG, 576, 0, stream>>>(x, rb, ypart, mstat, lstat, out);
    k_gemm64<1, YSEG, 1><<<192, 256, 0, stream>>>(ypart, qkv_w, qkv_b, cls, mstat, lstat);
    k_gemm64<2, 1><<<192, 256, 0, stream>>>(cls, proj_w, proj_b, out, nullptr, nullptr);
  } else {
    // Tier C: legacy verified pipeline (7.87 MB ws).
    float* y     = ws + 1328640;
    float* cls_c = ws + 1918464;
    k_zero<<<576, 256, 0, stream>>>(y);
    k_gemm64<0, 1><<<192, 256, 0, stream>>>(x, qkv_w, qkv_b, qf, nullptr, nullptr);
    k_r<<<96, 256, 0, stream>>>(qf, qkv_w, rb);
    k_logits<<<Bz * 10, 256, 0, stream>>>(x, rb, logits);
    k_softmax<<<Bz * Hh, 64, 0, stream>>>(logits, attnT);
    k_y_atomic<<<Bz * YSEG, 192, 0, stream>>>(x, attnT, y);
    k_gemm64<1, 1><<<192, 256, 0, stream>>>(y, qkv_w, qkv_b, cls_c, nullptr, nullptr);
    k_gemm64<2, 1><<<192, 256, 0, stream>>>(cls_c, proj_w, proj_b, out, nullptr, nullptr);
    k_copy<<<1024, 256, 0, stream>>>(x, out);
  }
}